// Round 14
// baseline (2805.370 us; speedup 1.0000x reference)
//
#include <hip/hip_runtime.h>
#include <stdint.h>

// Problem constants
#define Bn 256
#define Cn 512
#define Sn 256
#define En 512
#define Vn 1024

// ---------------------------------------------------------------------------
// stats: per (b,g) mean/rstd in fp64, folded into per-(b,c) scale/bias
// ---------------------------------------------------------------------------
__global__ __launch_bounds__(256) void stats_kernel(
    const float* __restrict__ x, const float* __restrict__ gamma,
    const float* __restrict__ beta, float* __restrict__ scale,
    float* __restrict__ bias)
{
  int blk = blockIdx.x;
  int b = blk >> 5, g = blk & 31;
  int tid = threadIdx.x;
  size_t base = ((size_t)(b * Cn + g * 16)) * Sn;
  double s1 = 0.0, s2 = 0.0;
#pragma unroll
  for (int k = 0; k < 16; ++k) {
    float v = x[base + (size_t)k * Sn + tid];
    s1 += v; s2 += (double)v * (double)v;
  }
  for (int off = 32; off > 0; off >>= 1) {
    s1 += __shfl_down(s1, off);
    s2 += __shfl_down(s2, off);
  }
  __shared__ double r1[4], r2[4];
  __shared__ float smean, srstd;
  int w = tid >> 6, lane = tid & 63;
  if (lane == 0) { r1[w] = s1; r2[w] = s2; }
  __syncthreads();
  if (tid == 0) {
    double S1 = r1[0] + r1[1] + r1[2] + r1[3];
    double S2 = r2[0] + r2[1] + r2[2] + r2[3];
    double mean = S1 / 4096.0;
    double var = S2 / 4096.0 - mean * mean;
    double rstd = 1.0 / sqrt(var + 1e-6);
    smean = (float)mean; srstd = (float)rstd;
  }
  __syncthreads();
  if (tid < 16) {
    int c = g * 16 + tid;
    float sc = srstd * gamma[c];
    scale[b * Cn + c] = sc;
    bias[b * Cn + c] = beta[c] - smean * sc;
  }
}

// ---------------------------------------------------------------------------
// e2: |emb_v|^2
// ---------------------------------------------------------------------------
__global__ __launch_bounds__(64) void e2_kernel(const float* __restrict__ emb,
                                                float* __restrict__ e2)
{
  int v = blockIdx.x, lane = threadIdx.x;
  float acc = 0.f;
#pragma unroll
  for (int k = 0; k < En / 64; ++k) {
    float e = emb[(size_t)v * En + lane + k * 64];
    acc += e * e;
  }
  for (int off = 32; off > 0; off >>= 1) acc += __shfl_down(acc, off);
  if (lane == 0) e2[v] = acc;
}

// ---------------------------------------------------------------------------
// transpose: in[R][C] -> out[C][R]
// ---------------------------------------------------------------------------
__global__ __launch_bounds__(256) void transpose_kernel(
    const float* __restrict__ in, float* __restrict__ out, int R, int C)
{
  __shared__ float t[32][33];
  int lx = threadIdx.x & 31, ly = threadIdx.x >> 5;
  int c0 = blockIdx.x * 32, r0 = blockIdx.y * 32;
#pragma unroll
  for (int k = 0; k < 32; k += 8)
    t[ly + k][lx] = in[(size_t)(r0 + ly + k) * C + c0 + lx];
  __syncthreads();
#pragma unroll
  for (int k = 0; k < 32; k += 8)
    out[(size_t)(c0 + ly + k) * R + r0 + lx] = t[lx][ly + k];
}

// ---------------------------------------------------------------------------
// R[v][c] = sum_e emb[v][e] * w_post[c][e] + b_post[c]
// ---------------------------------------------------------------------------
__global__ __launch_bounds__(256) void r_kernel(
    const float* __restrict__ emb, const float* __restrict__ w_post,
    const float* __restrict__ b_post, float* __restrict__ Rout)
{
  __shared__ float ea[64][33];
  __shared__ float wa[64][33];
  int v0 = (blockIdx.x >> 3) * 64;
  int c0 = (blockIdx.x & 7) * 64;
  int tid = threadIdx.x;
  int tv = tid >> 4, tc = tid & 15;
  float acc[4][4] = {};
  int v_l = tid >> 2, est = (tid & 3) << 3;
  for (int ek = 0; ek < En / 32; ++ek) {
#pragma unroll
    for (int k = 0; k < 8; ++k) {
      ea[v_l][est + k] = emb[(size_t)(v0 + v_l) * En + ek * 32 + est + k];
      wa[v_l][est + k] = w_post[(size_t)(c0 + v_l) * En + ek * 32 + est + k];
    }
    __syncthreads();
#pragma unroll
    for (int e = 0; e < 32; ++e)
#pragma unroll
      for (int i = 0; i < 4; ++i)
#pragma unroll
        for (int j = 0; j < 4; ++j)
          acc[i][j] += ea[tv * 4 + i][e] * wa[tc * 4 + j][e];
    __syncthreads();
  }
#pragma unroll
  for (int i = 0; i < 4; ++i)
#pragma unroll
    for (int j = 0; j < 4; ++j)
      Rout[(size_t)(v0 + tv * 4 + i) * Cn + c0 + tc * 4 + j] =
          acc[i][j] + b_post[c0 + tc * 4 + j];
}

// ---------------------------------------------------------------------------
// gemm1: z[e][s] = sum_c w_pre[e][c] * (x*sc+bi)   fp32, reg-tiled (PROVEN)
// ---------------------------------------------------------------------------
__global__ __launch_bounds__(256, 2) void gemm1_kernel(
    const float* __restrict__ x, const float* __restrict__ wT,
    const float* __restrict__ scale, const float* __restrict__ bias,
    float* __restrict__ out_z)
{
  __shared__ float wch[2][8][128];
  __shared__ float xch[2][8][128];

  const int tid = threadIdx.x;
  const int b  = blockIdx.x >> 3;
  const int e0 = ((blockIdx.x >> 1) & 3) * 128;
  const int s0 = (blockIdx.x & 1) * 128;
  const int te = tid >> 4, ts = tid & 15;
  const int stc = tid >> 5, sto = (tid & 31) * 4;

  float acc[8][8] = {};

  {
    int cg = stc;
    float4 wv = *(const float4*)&wT[(size_t)cg * En + e0 + sto];
    *(float4*)&wch[0][stc][sto] = wv;
    float sc = scale[b * Cn + cg], bi = bias[b * Cn + cg];
    float4 xv = *(const float4*)&x[((size_t)(b * Cn + cg)) * Sn + s0 + sto];
    float4 o;
    o.x = xv.x * sc + bi; o.y = xv.y * sc + bi;
    o.z = xv.z * sc + bi; o.w = xv.w * sc + bi;
    *(float4*)&xch[0][stc][sto] = o;
  }
  __syncthreads();

  for (int cc = 0; cc < 64; ++cc) {
    int d = cc & 1;
    float4 wpre, xpre; float scp = 0.f, bip = 0.f;
    if (cc < 63) {
      int cg = (cc + 1) * 8 + stc;
      wpre = *(const float4*)&wT[(size_t)cg * En + e0 + sto];
      scp = scale[b * Cn + cg]; bip = bias[b * Cn + cg];
      xpre = *(const float4*)&x[((size_t)(b * Cn + cg)) * Sn + s0 + sto];
    }
#pragma unroll
    for (int c = 0; c < 8; ++c) {
      float ww[8] __attribute__((aligned(16)));
      float xx[8] __attribute__((aligned(16)));
      *(float4*)&ww[0] = *(const float4*)&wch[d][c][te * 8];
      *(float4*)&ww[4] = *(const float4*)&wch[d][c][te * 8 + 4];
      *(float4*)&xx[0] = *(const float4*)&xch[d][c][ts * 4];
      *(float4*)&xx[4] = *(const float4*)&xch[d][c][64 + ts * 4];
#pragma unroll
      for (int i = 0; i < 8; ++i)
#pragma unroll
        for (int j = 0; j < 8; ++j)
          acc[i][j] += ww[i] * xx[j];
    }
    if (cc < 63) {
      int dn = d ^ 1;
      *(float4*)&wch[dn][stc][sto] = wpre;
      float4 o;
      o.x = xpre.x * scp + bip; o.y = xpre.y * scp + bip;
      o.z = xpre.z * scp + bip; o.w = xpre.w * scp + bip;
      *(float4*)&xch[dn][stc][sto] = o;
    }
    __syncthreads();
  }

#pragma unroll
  for (int i = 0; i < 8; ++i) {
    int e = e0 + te * 8 + i;
    size_t base = ((size_t)(b * En + e)) * Sn + s0;
    float4 lo, hi;
    lo.x = acc[i][0]; lo.y = acc[i][1]; lo.z = acc[i][2]; lo.w = acc[i][3];
    hi.x = acc[i][4]; hi.y = acc[i][5]; hi.z = acc[i][6]; hi.w = acc[i][7];
    *(float4*)&out_z[base + ts * 4] = lo;
    *(float4*)&out_z[base + 64 + ts * 4] = hi;
  }
}

// ---------------------------------------------------------------------------
// gemm2 + argmin over ALL 1024 v (R7-proven serial-chain arithmetic per
// (v,s); retiled 16v x 8s = 128 acc for 1.33x more FMA per LDS byte).
//   dist = (|z_s|^2 + |e_v|^2) - 2 <emb_v, z_s>
// block = (b, 32-s tile); 256 threads; vg=tid>>2 (16 v each), sg=tid&3 (8 s).
// et [8][1024] single-buffered (32 KB); writes tokens directly (no merge).
// ---------------------------------------------------------------------------
__global__ __launch_bounds__(256, 1) void gemm2_kernel(
    const float* __restrict__ z, const float* __restrict__ embT,
    const float* __restrict__ e2, float* __restrict__ out_tok,
    int* __restrict__ tok_ws)
{
  __shared__ float  et[8][1024];    // 32 KB (dead after main loop)
  __shared__ float  zch[2][8][32];  //  2 KB
  __shared__ double z2p[32][8];     //  2 KB
  __shared__ float  z2s[32];

  const int tid = threadIdx.x;
  const int sg = tid & 3, vg = tid >> 2;              // vg 0..63
  const int b = blockIdx.x >> 3, s0 = (blockIdx.x & 7) * 32;
  const int zse = tid >> 5, zss = tid & 31;           // z staging: (e-row, s)
  const int erow = tid >> 5, ecol = (tid & 31) * 4;   // et staging: row, col4

  double z2d = 0.0;

  // prologue: stage z chunk 0 + et chunk 0
  {
    float zv = z[((size_t)(b * En + zse)) * Sn + s0 + zss];
    zch[0][zse][zss] = zv;
    z2d += (double)zv * (double)zv;
    float4 ep[8];
#pragma unroll
    for (int m = 0; m < 8; ++m)
      ep[m] = *(const float4*)&embT[(size_t)erow * Vn + ecol + m * 128];
#pragma unroll
    for (int m = 0; m < 8; ++m)
      *(float4*)&et[erow][ecol + m * 128] = ep[m];
  }
  __syncthreads();

  float acc[4][4][8] = {};   // [q][i][j]: v = q*256+vg*4+i, s = sg*8+j

  for (int ch = 0; ch < 64; ++ch) {
    int d = ch & 1;
    float zvn = 0.f;
    float4 ep[8];
    if (ch < 63) {
      int e = (ch + 1) * 8;
      zvn = z[((size_t)(b * En + e + zse)) * Sn + s0 + zss];
#pragma unroll
      for (int m = 0; m < 8; ++m)
        ep[m] = *(const float4*)&embT[(size_t)(e + erow) * Vn + ecol + m * 128];
    }
#pragma unroll
    for (int c = 0; c < 8; ++c) {
      float zz[8] __attribute__((aligned(16)));
      float vv[16] __attribute__((aligned(16)));
      *(float4*)&zz[0] = *(const float4*)&zch[d][c][sg * 8];
      *(float4*)&zz[4] = *(const float4*)&zch[d][c][sg * 8 + 4];
#pragma unroll
      for (int q = 0; q < 4; ++q)
        *(float4*)&vv[q * 4] = *(const float4*)&et[c][q * 256 + vg * 4];
#pragma unroll
      for (int q = 0; q < 4; ++q)
#pragma unroll
        for (int i = 0; i < 4; ++i)
#pragma unroll
          for (int j = 0; j < 8; ++j)
            acc[q][i][j] += vv[q * 4 + i] * zz[j];
    }
    if (ch < 63) {
      zch[d ^ 1][zse][zss] = zvn;
      z2d += (double)zvn * (double)zvn;
    }
    __syncthreads();             // all reads of et chunk ch (and zch[d]) done
    if (ch < 63) {
#pragma unroll
      for (int m = 0; m < 8; ++m)
        *(float4*)&et[erow][ecol + m * 128] = ep[m];
    }
    __syncthreads();             // et chunk ch+1 visible
  }

  // ---- z2 reduce (fp64, fixed seg order; identical to R13) ----
  z2p[zss][zse] = z2d;
  __syncthreads();
  if (tid < 32) {
    double a = 0.0;
#pragma unroll
    for (int g = 0; g < 8; ++g) a += z2p[tid][g];
    z2s[tid] = (float)a;
  }
  __syncthreads();

  float z2r[8];
#pragma unroll
  for (int j = 0; j < 8; ++j) z2r[j] = z2s[sg * 8 + j];

  // ---- scoring + per-thread argmin (ascending v, strict <) ----
  float bv[8]; int bix[8];
#pragma unroll
  for (int j = 0; j < 8; ++j) { bv[j] = 3.0e38f; bix[j] = 0; }
#pragma unroll
  for (int q = 0; q < 4; ++q)
#pragma unroll
    for (int i = 0; i < 4; ++i) {
      int v = q * 256 + vg * 4 + i;
      float ee2 = e2[v];
#pragma unroll
      for (int j = 0; j < 8; ++j) {
        float t = z2r[j] + ee2;
        float sc = t - 2.f * acc[q][i][j];
        if (sc < bv[j]) { bv[j] = sc; bix[j] = v; }
      }
    }

  // ---- cross-thread lexicographic reduce (rvv/rii overlay dead et) ----
  float* rvv = (float*)&et[0][0];            // [64][32] = 8 KB
  int*   rii = (int*)&et[2][0];              // [64][32] = 8 KB
  *(float4*)&rvv[vg * 32 + sg * 8]     = *(float4*)&bv[0];
  *(float4*)&rvv[vg * 32 + sg * 8 + 4] = *(float4*)&bv[4];
  *(int4*)&rii[vg * 32 + sg * 8]       = *(int4*)&bix[0];
  *(int4*)&rii[vg * 32 + sg * 8 + 4]   = *(int4*)&bix[4];
  __syncthreads();
  if (tid < 32) {
    float bvv = 3.0e38f; int bii = 0;
    for (int t = 0; t < 64; ++t) {
      float vv2 = rvv[t * 32 + tid]; int ii = rii[t * 32 + tid];
      if (vv2 < bvv || (vv2 == bvv && ii < bii)) { bvv = vv2; bii = ii; }
    }
    int n = b * Sn + s0 + tid;
    tok_ws[n] = bii;
    out_tok[n] = (float)bii;
  }
}

// ---------------------------------------------------------------------------
// gather: z_q[b][e][s] = emb[tok][e] ; rec[b][c][s] = R[tok][c]
// ---------------------------------------------------------------------------
__global__ __launch_bounds__(256) void gather_kernel(
    const int* __restrict__ tok, const float* __restrict__ emb,
    const float* __restrict__ Rt, float* __restrict__ out_zq,
    float* __restrict__ out_rec)
{
  int bq = blockIdx.x;
  int b = bq >> 2, p = bq & 3;
  int s = threadIdx.x;
  unsigned tu = (unsigned)tok[b * Sn + s];
  if (tu > 1023u) tu = 0u;
  const float* erow = emb + (size_t)tu * En;
  const float* rrow = Rt + (size_t)tu * Cn;
#pragma unroll 4
  for (int r = 0; r < 128; ++r) {
    int e = p * 128 + r;
    out_zq[((size_t)(b * En + e)) * Sn + s] = erow[e];
    out_rec[((size_t)(b * Cn + e)) * Sn + s] = rrow[e];
  }
}

// ---------------------------------------------------------------------------
extern "C" void kernel_launch(void* const* d_in, const int* in_sizes, int n_in,
                              void* d_out, int out_size, void* d_ws, size_t ws_size,
                              hipStream_t stream) {
  const float* x      = (const float*)d_in[0];
  const float* gamma  = (const float*)d_in[1];
  const float* beta   = (const float*)d_in[2];
  const float* w_pre  = (const float*)d_in[3];
  const float* emb    = (const float*)d_in[4];
  const float* w_post = (const float*)d_in[5];
  const float* b_post = (const float*)d_in[6];

  float* out     = (float*)d_out;
  float* out_z   = out;
  float* out_zq  = out + (size_t)Bn * En * Sn;
  float* out_tok = out_zq + (size_t)Bn * En * Sn;
  float* out_rec = out_tok + (size_t)Bn * Sn;

  // ws: proven 3.41 MB footprint
  float* scale = (float*)d_ws;                     // [256*512]
  float* bias  = scale + Bn * Cn;                  // [256*512]
  float* e2    = bias + Bn * Cn;                   // [1024]
  float* R     = e2 + Vn;                          // [1024*512]
  int*   tokw  = (int*)(R + (size_t)Vn * Cn);      // [65536]

  // scribble inside out_rec (gather rewrites it last):
  float* wT    = out_rec;                          // [512*512]  w_T[c][e]
  float* embT  = out_rec + (size_t)Cn * En;        // [512*1024] emb_T[e][v]

  hipMemsetAsync(tokw, 0, (size_t)Bn * Sn * sizeof(int), stream);  // defensive
  stats_kernel<<<Bn * 32, 256, 0, stream>>>(x, gamma, beta, scale, bias);
  e2_kernel<<<Vn, 64, 0, stream>>>(emb, e2);
  transpose_kernel<<<dim3(Cn / 32, En / 32), 256, 0, stream>>>(w_pre, wT, En, Cn);
  transpose_kernel<<<dim3(En / 32, Vn / 32), 256, 0, stream>>>(emb, embT, Vn, En);
  r_kernel<<<128, 256, 0, stream>>>(emb, w_post, b_post, R);
  gemm1_kernel<<<Bn * 8, 256, 0, stream>>>(x, wT, scale, bias, out_z);
  gemm2_kernel<<<Bn * 8, 256, 0, stream>>>(out_z, embT, e2, out_tok, tokw);
  gather_kernel<<<Bn * 4, 256, 0, stream>>>(tokw, emb, R, out_zq, out_rec);
}

// Round 15
// 2530.468 us; speedup vs baseline: 1.1086x; 1.1086x over previous
//
#include <hip/hip_runtime.h>
#include <stdint.h>

// Problem constants
#define Bn 256
#define Cn 512
#define Sn 256
#define En 512
#define Vn 1024

// ---------------------------------------------------------------------------
// stats: per (b,g) mean/rstd in fp64, folded into per-(b,c) scale/bias
// ---------------------------------------------------------------------------
__global__ __launch_bounds__(256) void stats_kernel(
    const float* __restrict__ x, const float* __restrict__ gamma,
    const float* __restrict__ beta, float* __restrict__ scale,
    float* __restrict__ bias)
{
  int blk = blockIdx.x;
  int b = blk >> 5, g = blk & 31;
  int tid = threadIdx.x;
  size_t base = ((size_t)(b * Cn + g * 16)) * Sn;
  double s1 = 0.0, s2 = 0.0;
#pragma unroll
  for (int k = 0; k < 16; ++k) {
    float v = x[base + (size_t)k * Sn + tid];
    s1 += v; s2 += (double)v * (double)v;
  }
  for (int off = 32; off > 0; off >>= 1) {
    s1 += __shfl_down(s1, off);
    s2 += __shfl_down(s2, off);
  }
  __shared__ double r1[4], r2[4];
  __shared__ float smean, srstd;
  int w = tid >> 6, lane = tid & 63;
  if (lane == 0) { r1[w] = s1; r2[w] = s2; }
  __syncthreads();
  if (tid == 0) {
    double S1 = r1[0] + r1[1] + r1[2] + r1[3];
    double S2 = r2[0] + r2[1] + r2[2] + r2[3];
    double mean = S1 / 4096.0;
    double var = S2 / 4096.0 - mean * mean;
    double rstd = 1.0 / sqrt(var + 1e-6);
    smean = (float)mean; srstd = (float)rstd;
  }
  __syncthreads();
  if (tid < 16) {
    int c = g * 16 + tid;
    float sc = srstd * gamma[c];
    scale[b * Cn + c] = sc;
    bias[b * Cn + c] = beta[c] - smean * sc;
  }
}

// ---------------------------------------------------------------------------
// e2: |emb_v|^2
// ---------------------------------------------------------------------------
__global__ __launch_bounds__(64) void e2_kernel(const float* __restrict__ emb,
                                                float* __restrict__ e2)
{
  int v = blockIdx.x, lane = threadIdx.x;
  float acc = 0.f;
#pragma unroll
  for (int k = 0; k < En / 64; ++k) {
    float e = emb[(size_t)v * En + lane + k * 64];
    acc += e * e;
  }
  for (int off = 32; off > 0; off >>= 1) acc += __shfl_down(acc, off);
  if (lane == 0) e2[v] = acc;
}

// ---------------------------------------------------------------------------
// transpose: in[R][C] -> out[C][R]
// ---------------------------------------------------------------------------
__global__ __launch_bounds__(256) void transpose_kernel(
    const float* __restrict__ in, float* __restrict__ out, int R, int C)
{
  __shared__ float t[32][33];
  int lx = threadIdx.x & 31, ly = threadIdx.x >> 5;
  int c0 = blockIdx.x * 32, r0 = blockIdx.y * 32;
#pragma unroll
  for (int k = 0; k < 32; k += 8)
    t[ly + k][lx] = in[(size_t)(r0 + ly + k) * C + c0 + lx];
  __syncthreads();
#pragma unroll
  for (int k = 0; k < 32; k += 8)
    out[(size_t)(c0 + ly + k) * R + r0 + lx] = t[lx][ly + k];
}

// ---------------------------------------------------------------------------
// R[v][c] = sum_e emb[v][e] * w_post[c][e] + b_post[c]
// ---------------------------------------------------------------------------
__global__ __launch_bounds__(256) void r_kernel(
    const float* __restrict__ emb, const float* __restrict__ w_post,
    const float* __restrict__ b_post, float* __restrict__ Rout)
{
  __shared__ float ea[64][33];
  __shared__ float wa[64][33];
  int v0 = (blockIdx.x >> 3) * 64;
  int c0 = (blockIdx.x & 7) * 64;
  int tid = threadIdx.x;
  int tv = tid >> 4, tc = tid & 15;
  float acc[4][4] = {};
  int v_l = tid >> 2, est = (tid & 3) << 3;
  for (int ek = 0; ek < En / 32; ++ek) {
#pragma unroll
    for (int k = 0; k < 8; ++k) {
      ea[v_l][est + k] = emb[(size_t)(v0 + v_l) * En + ek * 32 + est + k];
      wa[v_l][est + k] = w_post[(size_t)(c0 + v_l) * En + ek * 32 + est + k];
    }
    __syncthreads();
#pragma unroll
    for (int e = 0; e < 32; ++e)
#pragma unroll
      for (int i = 0; i < 4; ++i)
#pragma unroll
        for (int j = 0; j < 4; ++j)
          acc[i][j] += ea[tv * 4 + i][e] * wa[tc * 4 + j][e];
    __syncthreads();
  }
#pragma unroll
  for (int i = 0; i < 4; ++i)
#pragma unroll
    for (int j = 0; j < 4; ++j)
      Rout[(size_t)(v0 + tv * 4 + i) * Cn + c0 + tc * 4 + j] =
          acc[i][j] + b_post[c0 + tc * 4 + j];
}

// ---------------------------------------------------------------------------
// gemm1: z[e][s] = sum_c w_pre[e][c] * (x*sc+bi)   fp32, reg-tiled (PROVEN)
// ---------------------------------------------------------------------------
__global__ __launch_bounds__(256, 2) void gemm1_kernel(
    const float* __restrict__ x, const float* __restrict__ wT,
    const float* __restrict__ scale, const float* __restrict__ bias,
    float* __restrict__ out_z)
{
  __shared__ float wch[2][8][128];
  __shared__ float xch[2][8][128];

  const int tid = threadIdx.x;
  const int b  = blockIdx.x >> 3;
  const int e0 = ((blockIdx.x >> 1) & 3) * 128;
  const int s0 = (blockIdx.x & 1) * 128;
  const int te = tid >> 4, ts = tid & 15;
  const int stc = tid >> 5, sto = (tid & 31) * 4;

  float acc[8][8] = {};

  {
    int cg = stc;
    float4 wv = *(const float4*)&wT[(size_t)cg * En + e0 + sto];
    *(float4*)&wch[0][stc][sto] = wv;
    float sc = scale[b * Cn + cg], bi = bias[b * Cn + cg];
    float4 xv = *(const float4*)&x[((size_t)(b * Cn + cg)) * Sn + s0 + sto];
    float4 o;
    o.x = xv.x * sc + bi; o.y = xv.y * sc + bi;
    o.z = xv.z * sc + bi; o.w = xv.w * sc + bi;
    *(float4*)&xch[0][stc][sto] = o;
  }
  __syncthreads();

  for (int cc = 0; cc < 64; ++cc) {
    int d = cc & 1;
    float4 wpre, xpre; float scp = 0.f, bip = 0.f;
    if (cc < 63) {
      int cg = (cc + 1) * 8 + stc;
      wpre = *(const float4*)&wT[(size_t)cg * En + e0 + sto];
      scp = scale[b * Cn + cg]; bip = bias[b * Cn + cg];
      xpre = *(const float4*)&x[((size_t)(b * Cn + cg)) * Sn + s0 + sto];
    }
#pragma unroll
    for (int c = 0; c < 8; ++c) {
      float ww[8] __attribute__((aligned(16)));
      float xx[8] __attribute__((aligned(16)));
      *(float4*)&ww[0] = *(const float4*)&wch[d][c][te * 8];
      *(float4*)&ww[4] = *(const float4*)&wch[d][c][te * 8 + 4];
      *(float4*)&xx[0] = *(const float4*)&xch[d][c][ts * 4];
      *(float4*)&xx[4] = *(const float4*)&xch[d][c][64 + ts * 4];
#pragma unroll
      for (int i = 0; i < 8; ++i)
#pragma unroll
        for (int j = 0; j < 8; ++j)
          acc[i][j] += ww[i] * xx[j];
    }
    if (cc < 63) {
      int dn = d ^ 1;
      *(float4*)&wch[dn][stc][sto] = wpre;
      float4 o;
      o.x = xpre.x * scp + bip; o.y = xpre.y * scp + bip;
      o.z = xpre.z * scp + bip; o.w = xpre.w * scp + bip;
      *(float4*)&xch[dn][stc][sto] = o;
    }
    __syncthreads();
  }

#pragma unroll
  for (int i = 0; i < 8; ++i) {
    int e = e0 + te * 8 + i;
    size_t base = ((size_t)(b * En + e)) * Sn + s0;
    float4 lo, hi;
    lo.x = acc[i][0]; lo.y = acc[i][1]; lo.z = acc[i][2]; lo.w = acc[i][3];
    hi.x = acc[i][4]; hi.y = acc[i][5]; hi.z = acc[i][6]; hi.w = acc[i][7];
    *(float4*)&out_z[base + ts * 4] = lo;
    *(float4*)&out_z[base + 64 + ts * 4] = hi;
  }
}

// ---------------------------------------------------------------------------
// gemm2 + partial argmin over a 512-v half. R13-proven arithmetic verbatim
// (same per-(v,s) serial fp32 FMA chain in c-order, same z2, same argmin).
// CHANGE vs R13: the emb operand (vv) is read DIRECTLY from global embT
// (2 MB, L2-resident) instead of LDS-staged -> LDS pipe carries only the
// z tile. Values and FMA order identical -> tokens bit-identical.
// block = (b, 32-s tile, v-half); 256 threads; 8v x 8s; LDS = 20.3 KB.
// ---------------------------------------------------------------------------
__global__ __launch_bounds__(256, 4) void gemm2_kernel(
    const float* __restrict__ z, const float* __restrict__ embT,
    const float* __restrict__ e2, float* __restrict__ pv,
    int* __restrict__ pi)
{
  __shared__ float  zch[2][8][32];  //  2 KB
  __shared__ double z2p[32][8];     //  2 KB
  __shared__ float  z2s[32];
  __shared__ float  rvv[64][32];    //  8 KB
  __shared__ int    rii[64][32];    //  8 KB

  const int tid = threadIdx.x;
  const int sg = tid & 3, vg = tid >> 2;
  const int bi = blockIdx.x;
  const int b = bi >> 4, s0 = ((bi >> 1) & 7) * 32, vh = bi & 1;
  const int vbase = vh * 512;
  const int zse = tid >> 5, zss = tid & 31;           // z staging: (e-row, s)

  double z2d = 0.0;

  // prologue: stage z chunk 0
  {
    float zv = z[((size_t)(b * En + zse)) * Sn + s0 + zss];
    zch[0][zse][zss] = zv;
    z2d += (double)zv * (double)zv;
  }
  __syncthreads();

  float acc[2][4][8] = {};   // [q][i][j]: v_local = q*256+vg*4+i, s = sg*8+j

  const float* ebase0 = embT + (size_t)vbase + vg * 4;
  for (int ch = 0; ch < 64; ++ch) {
    int d = ch & 1;
    float zvn = 0.f;
    if (ch < 63) {
      int e = (ch + 1) * 8;
      zvn = z[((size_t)(b * En + e + zse)) * Sn + s0 + zss];
    }
    const float* ebase = ebase0 + (size_t)(ch * 8) * Vn;
#pragma unroll
    for (int c = 0; c < 8; ++c) {
      float zz[8] __attribute__((aligned(16)));
      float vv[8] __attribute__((aligned(16)));
      *(float4*)&zz[0] = *(const float4*)&zch[d][c][sg * 8];
      *(float4*)&zz[4] = *(const float4*)&zch[d][c][sg * 8 + 4];
      *(float4*)&vv[0] = *(const float4*)&ebase[(size_t)c * Vn];
      *(float4*)&vv[4] = *(const float4*)&ebase[(size_t)c * Vn + 256];
#pragma unroll
      for (int q = 0; q < 2; ++q)
#pragma unroll
        for (int i = 0; i < 4; ++i)
#pragma unroll
          for (int j = 0; j < 8; ++j)
            acc[q][i][j] += vv[q * 4 + i] * zz[j];
    }
    if (ch < 63) {
      zch[d ^ 1][zse][zss] = zvn;
      z2d += (double)zvn * (double)zvn;
    }
    __syncthreads();   // reads of zch[d] done before next iter overwrites it
  }

  // ---- z2 reduce (fp64, fixed seg order; identical to R13) ----
  z2p[zss][zse] = z2d;
  __syncthreads();
  if (tid < 32) {
    double a = 0.0;
#pragma unroll
    for (int g = 0; g < 8; ++g) a += z2p[tid][g];
    z2s[tid] = (float)a;
  }
  __syncthreads();

  float z2r[8];
#pragma unroll
  for (int j = 0; j < 8; ++j) z2r[j] = z2s[sg * 8 + j];

  // ---- scoring + per-thread argmin (ascending v, strict <) ----
  float bv[8]; int bix[8];
#pragma unroll
  for (int j = 0; j < 8; ++j) { bv[j] = 3.0e38f; bix[j] = 0; }
#pragma unroll
  for (int q = 0; q < 2; ++q)
#pragma unroll
    for (int i = 0; i < 4; ++i) {
      int vl = q * 256 + vg * 4 + i;
      float ee2 = e2[vbase + vl];
#pragma unroll
      for (int j = 0; j < 8; ++j) {
        float t = z2r[j] + ee2;
        float sc = t - 2.f * acc[q][i][j];
        if (sc < bv[j]) { bv[j] = sc; bix[j] = vbase + vl; }
      }
    }

  // ---- cross-thread lexicographic reduce ----
  *(float4*)&rvv[vg][sg * 8]     = *(float4*)&bv[0];
  *(float4*)&rvv[vg][sg * 8 + 4] = *(float4*)&bv[4];
  *(int4*)&rii[vg][sg * 8]       = *(int4*)&bix[0];
  *(int4*)&rii[vg][sg * 8 + 4]   = *(int4*)&bix[4];
  __syncthreads();
  if (tid < 32) {
    float bvv = 3.0e38f; int bii = 0;
    for (int t = 0; t < 64; ++t) {
      float vv2 = rvv[t][tid]; int ii = rii[t][tid];
      if (vv2 < bvv || (vv2 == bvv && ii < bii)) { bvv = vv2; bii = ii; }
    }
    int n = b * Sn + s0 + tid;
    pv[vh * (Bn * Sn) + n] = bvv;
    pi[vh * (Bn * Sn) + n] = bii;
  }
}

// ---------------------------------------------------------------------------
// merge: combine the two v-half candidates (lexicographic) -> tokens
// ---------------------------------------------------------------------------
__global__ __launch_bounds__(256) void merge_kernel(
    const float* __restrict__ pv, const int* __restrict__ pi,
    float* __restrict__ out_tok, int* __restrict__ tok_ws)
{
  int n = blockIdx.x * 256 + threadIdx.x;
  float v0 = pv[n], v1 = pv[Bn * Sn + n];
  int i0 = pi[n], i1 = pi[Bn * Sn + n];
  int bii = (v1 < v0) ? i1 : i0;   // half-0 indices are all smaller
  tok_ws[n] = bii;
  out_tok[n] = (float)bii;
}

// ---------------------------------------------------------------------------
// gather: z_q[b][e][s] = emb[tok][e] ; rec[b][c][s] = R[tok][c]
// ---------------------------------------------------------------------------
__global__ __launch_bounds__(256) void gather_kernel(
    const int* __restrict__ tok, const float* __restrict__ emb,
    const float* __restrict__ Rt, float* __restrict__ out_zq,
    float* __restrict__ out_rec)
{
  int bq = blockIdx.x;
  int b = bq >> 2, p = bq & 3;
  int s = threadIdx.x;
  unsigned tu = (unsigned)tok[b * Sn + s];
  if (tu > 1023u) tu = 0u;
  const float* erow = emb + (size_t)tu * En;
  const float* rrow = Rt + (size_t)tu * Cn;
#pragma unroll 4
  for (int r = 0; r < 128; ++r) {
    int e = p * 128 + r;
    out_zq[((size_t)(b * En + e)) * Sn + s] = erow[e];
    out_rec[((size_t)(b * Cn + e)) * Sn + s] = rrow[e];
  }
}

// ---------------------------------------------------------------------------
extern "C" void kernel_launch(void* const* d_in, const int* in_sizes, int n_in,
                              void* d_out, int out_size, void* d_ws, size_t ws_size,
                              hipStream_t stream) {
  const float* x      = (const float*)d_in[0];
  const float* gamma  = (const float*)d_in[1];
  const float* beta   = (const float*)d_in[2];
  const float* w_pre  = (const float*)d_in[3];
  const float* emb    = (const float*)d_in[4];
  const float* w_post = (const float*)d_in[5];
  const float* b_post = (const float*)d_in[6];

  float* out     = (float*)d_out;
  float* out_z   = out;
  float* out_zq  = out + (size_t)Bn * En * Sn;
  float* out_tok = out_zq + (size_t)Bn * En * Sn;
  float* out_rec = out_tok + (size_t)Bn * Sn;

  // ws: proven 3.41 MB footprint (R7/R13 layout, verbatim)
  float* scale = (float*)d_ws;                     // [256*512]
  float* bias  = scale + Bn * Cn;                  // [256*512]
  float* e2    = bias + Bn * Cn;                   // [1024]
  float* R     = e2 + Vn;                          // [1024*512]
  int*   tokw  = (int*)(R + (size_t)Vn * Cn);      // [65536]

  // scribble inside out_rec (gather rewrites it last) -- R13 layout verbatim:
  float* wT    = out_rec;                          // [512*512]  w_T[c][e]
  float* embT  = out_rec + (size_t)Cn * En;        // [512*1024] emb_T[e][v]
  float* pv    = out_rec + 786432;                 // [2][65536] partial vals
  int*   pi    = (int*)(out_rec + 917504);         // [2][65536] partial idx

  hipMemsetAsync(tokw, 0, (size_t)Bn * Sn * sizeof(int), stream);  // defensive
  stats_kernel<<<Bn * 32, 256, 0, stream>>>(x, gamma, beta, scale, bias);
  e2_kernel<<<Vn, 64, 0, stream>>>(emb, e2);
  transpose_kernel<<<dim3(Cn / 32, En / 32), 256, 0, stream>>>(w_pre, wT, En, Cn);
  transpose_kernel<<<dim3(En / 32, Vn / 32), 256, 0, stream>>>(emb, embT, Vn, En);
  r_kernel<<<128, 256, 0, stream>>>(emb, w_post, b_post, R);
  gemm1_kernel<<<Bn * 8, 256, 0, stream>>>(x, wT, scale, bias, out_z);
  gemm2_kernel<<<Bn * 16, 256, 0, stream>>>(out_z, embT, e2, pv, pi);
  merge_kernel<<<Bn, 256, 0, stream>>>(pv, pi, out_tok, tokw);
  gather_kernel<<<Bn * 4, 256, 0, stream>>>(tokw, emb, R, out_zq, out_rec);
}

// Round 16
// 1572.102 us; speedup vs baseline: 1.7845x; 1.6096x over previous
//
#include <hip/hip_runtime.h>
#include <stdint.h>

// Problem constants
#define Bn 256
#define Cn 512
#define Sn 256
#define En 512
#define Vn 1024

// ---------------------------------------------------------------------------
// stats: per (b,g) mean/rstd in fp64, folded into per-(b,c) scale/bias
// ---------------------------------------------------------------------------
__global__ __launch_bounds__(256) void stats_kernel(
    const float* __restrict__ x, const float* __restrict__ gamma,
    const float* __restrict__ beta, float* __restrict__ scale,
    float* __restrict__ bias)
{
  int blk = blockIdx.x;
  int b = blk >> 5, g = blk & 31;
  int tid = threadIdx.x;
  size_t base = ((size_t)(b * Cn + g * 16)) * Sn;
  double s1 = 0.0, s2 = 0.0;
#pragma unroll
  for (int k = 0; k < 16; ++k) {
    float v = x[base + (size_t)k * Sn + tid];
    s1 += v; s2 += (double)v * (double)v;
  }
  for (int off = 32; off > 0; off >>= 1) {
    s1 += __shfl_down(s1, off);
    s2 += __shfl_down(s2, off);
  }
  __shared__ double r1[4], r2[4];
  __shared__ float smean, srstd;
  int w = tid >> 6, lane = tid & 63;
  if (lane == 0) { r1[w] = s1; r2[w] = s2; }
  __syncthreads();
  if (tid == 0) {
    double S1 = r1[0] + r1[1] + r1[2] + r1[3];
    double S2 = r2[0] + r2[1] + r2[2] + r2[3];
    double mean = S1 / 4096.0;
    double var = S2 / 4096.0 - mean * mean;
    double rstd = 1.0 / sqrt(var + 1e-6);
    smean = (float)mean; srstd = (float)rstd;
  }
  __syncthreads();
  if (tid < 16) {
    int c = g * 16 + tid;
    float sc = srstd * gamma[c];
    scale[b * Cn + c] = sc;
    bias[b * Cn + c] = beta[c] - smean * sc;
  }
}

// ---------------------------------------------------------------------------
// e2: |emb_v|^2
// ---------------------------------------------------------------------------
__global__ __launch_bounds__(64) void e2_kernel(const float* __restrict__ emb,
                                                float* __restrict__ e2)
{
  int v = blockIdx.x, lane = threadIdx.x;
  float acc = 0.f;
#pragma unroll
  for (int k = 0; k < En / 64; ++k) {
    float e = emb[(size_t)v * En + lane + k * 64];
    acc += e * e;
  }
  for (int off = 32; off > 0; off >>= 1) acc += __shfl_down(acc, off);
  if (lane == 0) e2[v] = acc;
}

// ---------------------------------------------------------------------------
// transpose: in[R][C] -> out[C][R]
// ---------------------------------------------------------------------------
__global__ __launch_bounds__(256) void transpose_kernel(
    const float* __restrict__ in, float* __restrict__ out, int R, int C)
{
  __shared__ float t[32][33];
  int lx = threadIdx.x & 31, ly = threadIdx.x >> 5;
  int c0 = blockIdx.x * 32, r0 = blockIdx.y * 32;
#pragma unroll
  for (int k = 0; k < 32; k += 8)
    t[ly + k][lx] = in[(size_t)(r0 + ly + k) * C + c0 + lx];
  __syncthreads();
#pragma unroll
  for (int k = 0; k < 32; k += 8)
    out[(size_t)(c0 + ly + k) * R + r0 + lx] = t[lx][ly + k];
}

// ---------------------------------------------------------------------------
// R[v][c] = sum_e emb[v][e] * w_post[c][e] + b_post[c]
// ---------------------------------------------------------------------------
__global__ __launch_bounds__(256) void r_kernel(
    const float* __restrict__ emb, const float* __restrict__ w_post,
    const float* __restrict__ b_post, float* __restrict__ Rout)
{
  __shared__ float ea[64][33];
  __shared__ float wa[64][33];
  int v0 = (blockIdx.x >> 3) * 64;
  int c0 = (blockIdx.x & 7) * 64;
  int tid = threadIdx.x;
  int tv = tid >> 4, tc = tid & 15;
  float acc[4][4] = {};
  int v_l = tid >> 2, est = (tid & 3) << 3;
  for (int ek = 0; ek < En / 32; ++ek) {
#pragma unroll
    for (int k = 0; k < 8; ++k) {
      ea[v_l][est + k] = emb[(size_t)(v0 + v_l) * En + ek * 32 + est + k];
      wa[v_l][est + k] = w_post[(size_t)(c0 + v_l) * En + ek * 32 + est + k];
    }
    __syncthreads();
#pragma unroll
    for (int e = 0; e < 32; ++e)
#pragma unroll
      for (int i = 0; i < 4; ++i)
#pragma unroll
        for (int j = 0; j < 4; ++j)
          acc[i][j] += ea[tv * 4 + i][e] * wa[tc * 4 + j][e];
    __syncthreads();
  }
#pragma unroll
  for (int i = 0; i < 4; ++i)
#pragma unroll
    for (int j = 0; j < 4; ++j)
      Rout[(size_t)(v0 + tv * 4 + i) * Cn + c0 + tc * 4 + j] =
          acc[i][j] + b_post[c0 + tc * 4 + j];
}

// ---------------------------------------------------------------------------
// gemm1: z[e][s] = sum_c w_pre[e][c] * (x*sc+bi)   fp32, reg-tiled (PROVEN)
// ---------------------------------------------------------------------------
__global__ __launch_bounds__(256, 2) void gemm1_kernel(
    const float* __restrict__ x, const float* __restrict__ wT,
    const float* __restrict__ scale, const float* __restrict__ bias,
    float* __restrict__ out_z)
{
  __shared__ float wch[2][8][128];
  __shared__ float xch[2][8][128];

  const int tid = threadIdx.x;
  const int b  = blockIdx.x >> 3;
  const int e0 = ((blockIdx.x >> 1) & 3) * 128;
  const int s0 = (blockIdx.x & 1) * 128;
  const int te = tid >> 4, ts = tid & 15;
  const int stc = tid >> 5, sto = (tid & 31) * 4;

  float acc[8][8] = {};

  {
    int cg = stc;
    float4 wv = *(const float4*)&wT[(size_t)cg * En + e0 + sto];
    *(float4*)&wch[0][stc][sto] = wv;
    float sc = scale[b * Cn + cg], bi = bias[b * Cn + cg];
    float4 xv = *(const float4*)&x[((size_t)(b * Cn + cg)) * Sn + s0 + sto];
    float4 o;
    o.x = xv.x * sc + bi; o.y = xv.y * sc + bi;
    o.z = xv.z * sc + bi; o.w = xv.w * sc + bi;
    *(float4*)&xch[0][stc][sto] = o;
  }
  __syncthreads();

  for (int cc = 0; cc < 64; ++cc) {
    int d = cc & 1;
    float4 wpre, xpre; float scp = 0.f, bip = 0.f;
    if (cc < 63) {
      int cg = (cc + 1) * 8 + stc;
      wpre = *(const float4*)&wT[(size_t)cg * En + e0 + sto];
      scp = scale[b * Cn + cg]; bip = bias[b * Cn + cg];
      xpre = *(const float4*)&x[((size_t)(b * Cn + cg)) * Sn + s0 + sto];
    }
#pragma unroll
    for (int c = 0; c < 8; ++c) {
      float ww[8] __attribute__((aligned(16)));
      float xx[8] __attribute__((aligned(16)));
      *(float4*)&ww[0] = *(const float4*)&wch[d][c][te * 8];
      *(float4*)&ww[4] = *(const float4*)&wch[d][c][te * 8 + 4];
      *(float4*)&xx[0] = *(const float4*)&xch[d][c][ts * 4];
      *(float4*)&xx[4] = *(const float4*)&xch[d][c][64 + ts * 4];
#pragma unroll
      for (int i = 0; i < 8; ++i)
#pragma unroll
        for (int j = 0; j < 8; ++j)
          acc[i][j] += ww[i] * xx[j];
    }
    if (cc < 63) {
      int dn = d ^ 1;
      *(float4*)&wch[dn][stc][sto] = wpre;
      float4 o;
      o.x = xpre.x * scp + bip; o.y = xpre.y * scp + bip;
      o.z = xpre.z * scp + bip; o.w = xpre.w * scp + bip;
      *(float4*)&xch[dn][stc][sto] = o;
    }
    __syncthreads();
  }

#pragma unroll
  for (int i = 0; i < 8; ++i) {
    int e = e0 + te * 8 + i;
    size_t base = ((size_t)(b * En + e)) * Sn + s0;
    float4 lo, hi;
    lo.x = acc[i][0]; lo.y = acc[i][1]; lo.z = acc[i][2]; lo.w = acc[i][3];
    hi.x = acc[i][4]; hi.y = acc[i][5]; hi.z = acc[i][6]; hi.w = acc[i][7];
    *(float4*)&out_z[base + ts * 4] = lo;
    *(float4*)&out_z[base + 64 + ts * 4] = hi;
  }
}

// ---------------------------------------------------------------------------
// gemm2 + partial argmin over a 512-v half. R13-proven arithmetic verbatim.
// embT (vv) read directly from global (L2-resident); z tile LDS-staged.
// FIX vs R15: __launch_bounds__(256) with NO min-waves arg -- R15's (256,4)
// forced VGPR=64 and spilled the 64-acc block (WRITE_SIZE 36MB -> 2.2GB).
// block = (b, 32-s tile, v-half); 256 threads; 8v x 8s; LDS = 20.3 KB.
// ---------------------------------------------------------------------------
__global__ __launch_bounds__(256) void gemm2_kernel(
    const float* __restrict__ z, const float* __restrict__ embT,
    const float* __restrict__ e2, float* __restrict__ pv,
    int* __restrict__ pi)
{
  __shared__ float  zch[2][8][32];  //  2 KB
  __shared__ double z2p[32][8];     //  2 KB
  __shared__ float  z2s[32];
  __shared__ float  rvv[64][32];    //  8 KB
  __shared__ int    rii[64][32];    //  8 KB

  const int tid = threadIdx.x;
  const int sg = tid & 3, vg = tid >> 2;
  const int bi = blockIdx.x;
  const int b = bi >> 4, s0 = ((bi >> 1) & 7) * 32, vh = bi & 1;
  const int vbase = vh * 512;
  const int zse = tid >> 5, zss = tid & 31;           // z staging: (e-row, s)

  double z2d = 0.0;

  // prologue: stage z chunk 0
  {
    float zv = z[((size_t)(b * En + zse)) * Sn + s0 + zss];
    zch[0][zse][zss] = zv;
    z2d += (double)zv * (double)zv;
  }
  __syncthreads();

  float acc[2][4][8] = {};   // [q][i][j]: v_local = q*256+vg*4+i, s = sg*8+j

  const float* ebase0 = embT + (size_t)vbase + vg * 4;
  for (int ch = 0; ch < 64; ++ch) {
    int d = ch & 1;
    float zvn = 0.f;
    if (ch < 63) {
      int e = (ch + 1) * 8;
      zvn = z[((size_t)(b * En + e + zse)) * Sn + s0 + zss];
    }
    const float* ebase = ebase0 + (size_t)(ch * 8) * Vn;
#pragma unroll
    for (int c = 0; c < 8; ++c) {
      float zz[8] __attribute__((aligned(16)));
      float vv[8] __attribute__((aligned(16)));
      *(float4*)&zz[0] = *(const float4*)&zch[d][c][sg * 8];
      *(float4*)&zz[4] = *(const float4*)&zch[d][c][sg * 8 + 4];
      *(float4*)&vv[0] = *(const float4*)&ebase[(size_t)c * Vn];
      *(float4*)&vv[4] = *(const float4*)&ebase[(size_t)c * Vn + 256];
#pragma unroll
      for (int q = 0; q < 2; ++q)
#pragma unroll
        for (int i = 0; i < 4; ++i)
#pragma unroll
          for (int j = 0; j < 8; ++j)
            acc[q][i][j] += vv[q * 4 + i] * zz[j];
    }
    if (ch < 63) {
      zch[d ^ 1][zse][zss] = zvn;
      z2d += (double)zvn * (double)zvn;
    }
    __syncthreads();   // reads of zch[d] done before next iter overwrites it
  }

  // ---- z2 reduce (fp64, fixed seg order; identical to R13) ----
  z2p[zss][zse] = z2d;
  __syncthreads();
  if (tid < 32) {
    double a = 0.0;
#pragma unroll
    for (int g = 0; g < 8; ++g) a += z2p[tid][g];
    z2s[tid] = (float)a;
  }
  __syncthreads();

  float z2r[8];
#pragma unroll
  for (int j = 0; j < 8; ++j) z2r[j] = z2s[sg * 8 + j];

  // ---- scoring + per-thread argmin (ascending v, strict <) ----
  float bv[8]; int bix[8];
#pragma unroll
  for (int j = 0; j < 8; ++j) { bv[j] = 3.0e38f; bix[j] = 0; }
#pragma unroll
  for (int q = 0; q < 2; ++q)
#pragma unroll
    for (int i = 0; i < 4; ++i) {
      int vl = q * 256 + vg * 4 + i;
      float ee2 = e2[vbase + vl];
#pragma unroll
      for (int j = 0; j < 8; ++j) {
        float t = z2r[j] + ee2;
        float sc = t - 2.f * acc[q][i][j];
        if (sc < bv[j]) { bv[j] = sc; bix[j] = vbase + vl; }
      }
    }

  // ---- cross-thread lexicographic reduce ----
  *(float4*)&rvv[vg][sg * 8]     = *(float4*)&bv[0];
  *(float4*)&rvv[vg][sg * 8 + 4] = *(float4*)&bv[4];
  *(int4*)&rii[vg][sg * 8]       = *(int4*)&bix[0];
  *(int4*)&rii[vg][sg * 8 + 4]   = *(int4*)&bix[4];
  __syncthreads();
  if (tid < 32) {
    float bvv = 3.0e38f; int bii = 0;
    for (int t = 0; t < 64; ++t) {
      float vv2 = rvv[t][tid]; int ii = rii[t][tid];
      if (vv2 < bvv || (vv2 == bvv && ii < bii)) { bvv = vv2; bii = ii; }
    }
    int n = b * Sn + s0 + tid;
    pv[vh * (Bn * Sn) + n] = bvv;
    pi[vh * (Bn * Sn) + n] = bii;
  }
}

// ---------------------------------------------------------------------------
// merge: combine the two v-half candidates (lexicographic) -> tokens
// ---------------------------------------------------------------------------
__global__ __launch_bounds__(256) void merge_kernel(
    const float* __restrict__ pv, const int* __restrict__ pi,
    float* __restrict__ out_tok, int* __restrict__ tok_ws)
{
  int n = blockIdx.x * 256 + threadIdx.x;
  float v0 = pv[n], v1 = pv[Bn * Sn + n];
  int i0 = pi[n], i1 = pi[Bn * Sn + n];
  int bii = (v1 < v0) ? i1 : i0;   // half-0 indices are all smaller
  tok_ws[n] = bii;
  out_tok[n] = (float)bii;
}

// ---------------------------------------------------------------------------
// gather: z_q[b][e][s] = emb[tok][e] ; rec[b][c][s] = R[tok][c]
// ---------------------------------------------------------------------------
__global__ __launch_bounds__(256) void gather_kernel(
    const int* __restrict__ tok, const float* __restrict__ emb,
    const float* __restrict__ Rt, float* __restrict__ out_zq,
    float* __restrict__ out_rec)
{
  int bq = blockIdx.x;
  int b = bq >> 2, p = bq & 3;
  int s = threadIdx.x;
  unsigned tu = (unsigned)tok[b * Sn + s];
  if (tu > 1023u) tu = 0u;
  const float* erow = emb + (size_t)tu * En;
  const float* rrow = Rt + (size_t)tu * Cn;
#pragma unroll 4
  for (int r = 0; r < 128; ++r) {
    int e = p * 128 + r;
    out_zq[((size_t)(b * En + e)) * Sn + s] = erow[e];
    out_rec[((size_t)(b * Cn + e)) * Sn + s] = rrow[e];
  }
}

// ---------------------------------------------------------------------------
extern "C" void kernel_launch(void* const* d_in, const int* in_sizes, int n_in,
                              void* d_out, int out_size, void* d_ws, size_t ws_size,
                              hipStream_t stream) {
  const float* x      = (const float*)d_in[0];
  const float* gamma  = (const float*)d_in[1];
  const float* beta   = (const float*)d_in[2];
  const float* w_pre  = (const float*)d_in[3];
  const float* emb    = (const float*)d_in[4];
  const float* w_post = (const float*)d_in[5];
  const float* b_post = (const float*)d_in[6];

  float* out     = (float*)d_out;
  float* out_z   = out;
  float* out_zq  = out + (size_t)Bn * En * Sn;
  float* out_tok = out_zq + (size_t)Bn * En * Sn;
  float* out_rec = out_tok + (size_t)Bn * Sn;

  // ws: proven 3.41 MB footprint (R7/R13 layout, verbatim)
  float* scale = (float*)d_ws;                     // [256*512]
  float* bias  = scale + Bn * Cn;                  // [256*512]
  float* e2    = bias + Bn * Cn;                   // [1024]
  float* R     = e2 + Vn;                          // [1024*512]
  int*   tokw  = (int*)(R + (size_t)Vn * Cn);      // [65536]

  // scribble inside out_rec (gather rewrites it last) -- R13 layout verbatim:
  float* wT    = out_rec;                          // [512*512]  w_T[c][e]
  float* embT  = out_rec + (size_t)Cn * En;        // [512*1024] emb_T[e][v]
  float* pv    = out_rec + 786432;                 // [2][65536] partial vals
  int*   pi    = (int*)(out_rec + 917504);         // [2][65536] partial idx

  hipMemsetAsync(tokw, 0, (size_t)Bn * Sn * sizeof(int), stream);  // defensive
  stats_kernel<<<Bn * 32, 256, 0, stream>>>(x, gamma, beta, scale, bias);
  e2_kernel<<<Vn, 64, 0, stream>>>(emb, e2);
  transpose_kernel<<<dim3(Cn / 32, En / 32), 256, 0, stream>>>(w_pre, wT, En, Cn);
  transpose_kernel<<<dim3(En / 32, Vn / 32), 256, 0, stream>>>(emb, embT, Vn, En);
  r_kernel<<<128, 256, 0, stream>>>(emb, w_post, b_post, R);
  gemm1_kernel<<<Bn * 8, 256, 0, stream>>>(x, wT, scale, bias, out_z);
  gemm2_kernel<<<Bn * 16, 256, 0, stream>>>(out_z, embT, e2, pv, pi);
  merge_kernel<<<Bn, 256, 0, stream>>>(pv, pi, out_tok, tokw);
  gather_kernel<<<Bn * 4, 256, 0, stream>>>(tokw, emb, R, out_zq, out_rec);
}